// Round 3
// baseline (160.295 us; speedup 1.0000x reference)
//
#include <hip/hip_runtime.h>

// CurvatureLoss: out = sum(|lap(pred) - lap(target)| * mask) / (sum(mask) + 1e-8)
// lap = 3x3 Laplacian [[0,1,0],[1,-4,1],[0,1,0]], zero ("SAME") padding.
// Linearity: lap(pred)-lap(target) == lap(pred-target).
//
// R2: ROWS=16 strips (1.125x halo), register-rolling window, no LDS/barriers in
// the stencil loop, explicit 2-row-deep load pipeline (raw loads in flight,
// subtract at consume), XCD-chunked block swizzle (halo rows share an XCD L2),
// and fused last-block final reduction (no second kernel launch).
// Cross-XCD visibility of partial[] uses agent-scope atomic load/store --
// plain loads could see a stale reader-XCD L2 line from a previous replay.

static constexpr int IMG_W = 1024;   // fixed by reference
static constexpr int IMG_H = 1024;   // fixed by reference
static constexpr int ROWS  = 16;     // output rows per block
static constexpr int NT    = 256;    // 4 cols/thread at W=1024
static constexpr int NXCD  = 8;

__device__ __forceinline__ float4 f4sub(float4 a, float4 b) {
    return make_float4(a.x - b.x, a.y - b.y, a.z - b.z, a.w - b.w);
}

__global__ __launch_bounds__(NT, 4) void curv_kernel(
    const float* __restrict__ pred,
    const float* __restrict__ target,
    const float* __restrict__ mask,
    float* __restrict__ partial,        // [2 * nblocks] in d_ws
    unsigned int* __restrict__ counter, // zeroed via hipMemsetAsync each launch
    float* __restrict__ out,
    int H, int nblocks)
{
    // XCD-chunked swizzle: hw bid -> work id; consecutive work ids (adjacent
    // strips, sharing halo rows) execute on the same XCD. nblocks % 8 == 0.
    const int bid = blockIdx.x;
    const int cpx = nblocks / NXCD;
    const int wid = (bid % NXCD) * cpx + bid / NXCD;

    const int tid  = threadIdx.x;
    const int lane = tid & 63;
    const int bpi  = H / ROWS;                 // strips per image
    const int img  = wid / bpi;
    const int y0   = (wid % bpi) * ROWS;
    const size_t imgOff = (size_t)img * H * IMG_W;
    const int x4 = tid * 4;                    // this thread's 4 columns

    const float4 zero4 = make_float4(0.f, 0.f, 0.f, 0.f);
    auto raw = [&](const float* __restrict__ p, int y) -> float4 {
        return (y < 0 || y >= H) ? zero4
             : *reinterpret_cast<const float4*>(p + imgOff + (size_t)y * IMG_W + x4);
    };

    float4 P[2], T[2], M[2];
    float elP[2], elT[2], erP[2], erT[2];

    auto edgeRaw = [&](int y, int s) {
        elP[s] = 0.f; elT[s] = 0.f; erP[s] = 0.f; erT[s] = 0.f;
        if (lane == 0 && x4 != 0) {            // left neighbor of wave strip
            const size_t o = imgOff + (size_t)y * IMG_W + (x4 - 1);
            elP[s] = pred[o]; elT[s] = target[o];
        }
        if (lane == 63 && x4 + 4 != IMG_W) {   // right neighbor of wave strip
            const size_t o = imgOff + (size_t)y * IMG_W + (x4 + 4);
            erP[s] = pred[o]; erT[s] = target[o];
        }
    };

    // ---- Prologue: issue loads for rows y0-1 .. y0+2 before any math ----
    const float4 pA = raw(pred, y0 - 1), tA = raw(target, y0 - 1);
    const float4 pB = raw(pred, y0),     tB = raw(target, y0);
    P[0] = raw(pred, y0 + 1); T[0] = raw(target, y0 + 1);
    P[1] = raw(pred, y0 + 2); T[1] = raw(target, y0 + 2);
    M[0] = raw(mask, y0);     M[1] = raw(mask, y0 + 1);
    edgeRaw(y0, 0); edgeRaw(y0 + 1, 1);

    float4 dP = f4sub(pA, tA);   // d(y0-1)
    float4 dC = f4sub(pB, tB);   // d(y0)

    float lsum = 0.f, msum = 0.f;

    #pragma unroll
    for (int r = 0; r < ROWS; ++r) {
        const int s = r & 1;
        const float4 dN = f4sub(P[s], T[s]);   // d(y+1), loaded 2 iters ago
        const float4 m  = M[s];

        float left  = __shfl_up(dC.w, 1, 64);
        float right = __shfl_down(dC.x, 1, 64);
        if (lane == 0)  left  = elP[s] - elT[s];
        if (lane == 63) right = erP[s] - erT[s];

        const float l0 = dP.x + dN.x + left  + dC.y - 4.f * dC.x;
        const float l1 = dP.y + dN.y + dC.x  + dC.z - 4.f * dC.y;
        const float l2 = dP.z + dN.z + dC.y  + dC.w - 4.f * dC.z;
        const float l3 = dP.w + dN.w + dC.z  + right - 4.f * dC.w;

        lsum += fabsf(l0) * m.x + fabsf(l1) * m.y + fabsf(l2) * m.z + fabsf(l3) * m.w;
        msum += m.x + m.y + m.z + m.w;

        dP = dC; dC = dN;

        // Refill slot s (consumed this iteration) two rows ahead.
        const int y = y0 + r;
        if (r + 3 <= ROWS) { P[s] = raw(pred, y + 3); T[s] = raw(target, y + 3); }
        if (r + 2 <  ROWS) { M[s] = raw(mask, y + 2); edgeRaw(y + 2, s); }
    }

    // ---- Block reduction ----
    for (int off = 32; off > 0; off >>= 1) {
        lsum += __shfl_down(lsum, off, 64);
        msum += __shfl_down(msum, off, 64);
    }
    __shared__ float wls[NT / 64], wms[NT / 64];
    __shared__ unsigned int s_ticket;
    const int wave = tid >> 6;
    if (lane == 0) { wls[wave] = lsum; wms[wave] = msum; }
    __syncthreads();
    if (tid == 0) {
        float L = 0.f, Mm = 0.f;
        #pragma unroll
        for (int w = 0; w < NT / 64; ++w) { L += wls[w]; Mm += wms[w]; }
        // Agent-scope stores: must be visible to the last block on another XCD.
        __hip_atomic_store(&partial[2 * (size_t)wid],     L,  __ATOMIC_RELAXED, __HIP_MEMORY_SCOPE_AGENT);
        __hip_atomic_store(&partial[2 * (size_t)wid + 1], Mm, __ATOMIC_RELAXED, __HIP_MEMORY_SCOPE_AGENT);
        __threadfence();
        s_ticket = atomicAdd(counter, 1u);
    }
    __syncthreads();

    // ---- Last block performs the final reduction (deterministic order) ----
    if (s_ticket == (unsigned int)(nblocks - 1)) {
        __threadfence();
        float L = 0.f, Mm = 0.f;
        for (int i = tid; i < nblocks; i += NT) {
            L  += __hip_atomic_load(&partial[2 * (size_t)i],     __ATOMIC_RELAXED, __HIP_MEMORY_SCOPE_AGENT);
            Mm += __hip_atomic_load(&partial[2 * (size_t)i + 1], __ATOMIC_RELAXED, __HIP_MEMORY_SCOPE_AGENT);
        }
        for (int off = 32; off > 0; off >>= 1) {
            L  += __shfl_down(L, off, 64);
            Mm += __shfl_down(Mm, off, 64);
        }
        if (lane == 0) { wls[wave] = L; wms[wave] = Mm; }
        __syncthreads();
        if (tid == 0) {
            float LL = 0.f, MM = 0.f;
            #pragma unroll
            for (int w = 0; w < NT / 64; ++w) { LL += wls[w]; MM += wms[w]; }
            out[0] = LL / (MM + 1e-8f);
        }
    }
}

extern "C" void kernel_launch(void* const* d_in, const int* in_sizes, int n_in,
                              void* d_out, int out_size, void* d_ws, size_t ws_size,
                              hipStream_t stream) {
    const float* pred   = (const float*)d_in[0];
    const float* target = (const float*)d_in[1];
    const float* mask   = (const float*)d_in[2];
    float* out = (float*)d_out;

    const int H = IMG_H;
    const int B = in_sizes[0] / (IMG_H * IMG_W);
    const int nblocks = B * (H / ROWS);        // 16 * 64 = 1024

    float* partial = (float*)d_ws;                                   // 8 KB
    unsigned int* counter = (unsigned int*)((char*)d_ws + 16384);    // past partials

    hipMemsetAsync(counter, 0, sizeof(unsigned int), stream);
    curv_kernel<<<nblocks, NT, 0, stream>>>(pred, target, mask, partial, counter, out, H, nblocks);
}

// Round 4
// 69.165 us; speedup vs baseline: 2.3176x; 2.3176x over previous
//
#include <hip/hip_runtime.h>

// CurvatureLoss: out = sum(|lap(pred) - lap(target)| * mask) / (sum(mask) + 1e-8)
// lap = 3x3 Laplacian [[0,1,0],[1,-4,1],[0,1,0]], zero ("SAME") padding.
// Linearity: lap(pred)-lap(target) == lap(pred-target).
//
// R3 = R1's barrier-free register-rolling window (NAMED registers only --
// R2's pipeline arrays were demoted to scratch: 167 MB WRITE_SIZE, 4x slower)
// + R0's ROWS=16 geometry (1.125x halo, not R1's 1.25x)
// + R2's fused last-block final reduction (drops the second launch)
// + XCD-chunked swizzle (adjacent strips share halo rows in one XCD's L2).

static constexpr int IMG_W = 1024;   // fixed by reference
static constexpr int IMG_H = 1024;   // fixed by reference
static constexpr int ROWS  = 16;     // output rows per block
static constexpr int NT    = 256;    // 4 cols/thread at W=1024
static constexpr int NXCD  = 8;

__global__ __launch_bounds__(NT) void curv_kernel(
    const float* __restrict__ pred,
    const float* __restrict__ target,
    const float* __restrict__ mask,
    float* __restrict__ partial,        // [2 * nblocks] in d_ws
    unsigned int* __restrict__ counter, // zeroed via hipMemsetAsync each launch
    float* __restrict__ out,
    int H, int nblocks)
{
    // XCD-chunked swizzle: consecutive work ids (adjacent strips, sharing halo
    // rows) run on the same XCD. nblocks % 8 == 0 (1024).
    const int bid = blockIdx.x;
    const int cpx = nblocks / NXCD;
    const int wid = (bid % NXCD) * cpx + bid / NXCD;

    const int tid  = threadIdx.x;
    const int lane = tid & 63;
    const int bpi  = H / ROWS;                 // strips per image
    const int img  = wid / bpi;
    const int y0   = (wid % bpi) * ROWS;
    const size_t imgOff = (size_t)img * H * IMG_W;
    const int x4 = tid * 4;                    // this thread's 4 columns

    auto loadD = [&](int y) -> float4 {        // d = pred - target, zero-padded
        if (y < 0 || y >= H) return make_float4(0.f, 0.f, 0.f, 0.f);
        const size_t o = imgOff + (size_t)y * IMG_W + x4;
        const float4 p = *reinterpret_cast<const float4*>(pred + o);
        const float4 t = *reinterpret_cast<const float4*>(target + o);
        return make_float4(p.x - t.x, p.y - t.y, p.z - t.z, p.w - t.w);
    };

    float4 d_prev = loadD(y0 - 1);
    float4 d_cur  = loadD(y0);

    float lsum = 0.f, msum = 0.f;

    #pragma unroll
    for (int r = 0; r < ROWS; ++r) {
        const int y = y0 + r;
        const float4 d_next = loadD(y + 1);

        // Wave-strip edge neighbors of the center row (lanes 0 and 63 only;
        // the row was just loaded, these hit L1/L2).
        float eL = 0.f, eR = 0.f;
        if (lane == 0 && x4 != 0) {
            const size_t o = imgOff + (size_t)y * IMG_W + (x4 - 1);
            eL = pred[o] - target[o];
        }
        if (lane == 63 && x4 + 4 != IMG_W) {
            const size_t o = imgOff + (size_t)y * IMG_W + (x4 + 4);
            eR = pred[o] - target[o];
        }

        float left  = __shfl_up(d_cur.w, 1, 64);
        float right = __shfl_down(d_cur.x, 1, 64);
        if (lane == 0)  left  = eL;
        if (lane == 63) right = eR;

        const float4 m = *reinterpret_cast<const float4*>(
            mask + imgOff + (size_t)y * IMG_W + x4);

        const float l0 = d_prev.x + d_next.x + left    + d_cur.y - 4.f * d_cur.x;
        const float l1 = d_prev.y + d_next.y + d_cur.x + d_cur.z - 4.f * d_cur.y;
        const float l2 = d_prev.z + d_next.z + d_cur.y + d_cur.w - 4.f * d_cur.z;
        const float l3 = d_prev.w + d_next.w + d_cur.z + right   - 4.f * d_cur.w;

        lsum += fabsf(l0) * m.x + fabsf(l1) * m.y + fabsf(l2) * m.z + fabsf(l3) * m.w;
        msum += m.x + m.y + m.z + m.w;

        d_prev = d_cur;
        d_cur  = d_next;
    }

    // ---- Block reduction ----
    for (int off = 32; off > 0; off >>= 1) {
        lsum += __shfl_down(lsum, off, 64);
        msum += __shfl_down(msum, off, 64);
    }
    __shared__ float wls[NT / 64], wms[NT / 64];
    __shared__ unsigned int s_ticket;
    const int wave = tid >> 6;
    if (lane == 0) { wls[wave] = lsum; wms[wave] = msum; }
    __syncthreads();
    if (tid == 0) {
        float L = 0.f, Mm = 0.f;
        #pragma unroll
        for (int w = 0; w < NT / 64; ++w) { L += wls[w]; Mm += wms[w]; }
        // Agent-scope: must be visible to the last block on another XCD.
        __hip_atomic_store(&partial[2 * (size_t)wid],     L,  __ATOMIC_RELAXED, __HIP_MEMORY_SCOPE_AGENT);
        __hip_atomic_store(&partial[2 * (size_t)wid + 1], Mm, __ATOMIC_RELAXED, __HIP_MEMORY_SCOPE_AGENT);
        __threadfence();
        s_ticket = atomicAdd(counter, 1u);
    }
    __syncthreads();

    // ---- Last block to finish reduces all partials (deterministic order) ----
    if (s_ticket == (unsigned int)(nblocks - 1)) {
        __threadfence();
        float L = 0.f, Mm = 0.f;
        for (int i = tid; i < nblocks; i += NT) {
            L  += __hip_atomic_load(&partial[2 * (size_t)i],     __ATOMIC_RELAXED, __HIP_MEMORY_SCOPE_AGENT);
            Mm += __hip_atomic_load(&partial[2 * (size_t)i + 1], __ATOMIC_RELAXED, __HIP_MEMORY_SCOPE_AGENT);
        }
        for (int off = 32; off > 0; off >>= 1) {
            L  += __shfl_down(L, off, 64);
            Mm += __shfl_down(Mm, off, 64);
        }
        if (lane == 0) { wls[wave] = L; wms[wave] = Mm; }
        __syncthreads();
        if (tid == 0) {
            float LL = 0.f, MM = 0.f;
            #pragma unroll
            for (int w = 0; w < NT / 64; ++w) { LL += wls[w]; MM += wms[w]; }
            out[0] = LL / (MM + 1e-8f);
        }
    }
}

extern "C" void kernel_launch(void* const* d_in, const int* in_sizes, int n_in,
                              void* d_out, int out_size, void* d_ws, size_t ws_size,
                              hipStream_t stream) {
    const float* pred   = (const float*)d_in[0];
    const float* target = (const float*)d_in[1];
    const float* mask   = (const float*)d_in[2];
    float* out = (float*)d_out;

    const int H = IMG_H;
    const int B = in_sizes[0] / (IMG_H * IMG_W);
    const int nblocks = B * (H / ROWS);        // 16 * 64 = 1024

    float* partial = (float*)d_ws;                                   // 8 KB
    unsigned int* counter = (unsigned int*)((char*)d_ws + 16384);

    hipMemsetAsync(counter, 0, sizeof(unsigned int), stream);
    curv_kernel<<<nblocks, NT, 0, stream>>>(pred, target, mask, partial, counter, out, H, nblocks);
}